// Round 1
// baseline (44.901 us; speedup 1.0000x reference)
//
#include <hip/hip_runtime.h>
#include <hip/hip_bf16.h>

// Problem constants: B=64, S=512, N=32768, D=256, H=4, HD=64, T=24, scale=1/8.
//
// Workspace layout (floats):
//   qu [B][256]      : Wq(:, :256) @ user_pref[user[b]]          (16384)
//   qt [T][256]      : Wq(:, 256:) @ ts[t] + bq                  (6144)
//   kk [H][T][64]    : Wk @ ts[t] + bk                            (6144)
//   vv [H][T][64]    : Wv @ ts[t] + bv                            (6144)
//   WuT[256][256]    : Wu transposed                              (65536)
//   vW [96][256]     : folded V*Wu  (ht = h*24+t)                 (24576)
//   EU [B][H][T]     : exp(scale * qu.k)                          (6144)
//   ET [T][H][T]     : exp(scale * qt.k)                          (2304)
#define QU_OFF   0
#define QT_OFF   16384
#define KK_OFF   22528
#define VV_OFF   28672
#define WUT_OFF  34816
#define VW_OFF   100352
#define EU_OFF   124928
#define ET_OFF   131072
// total ws: 133376 floats = 533.5 KB

// ---------- Kernel A: projection rows (one wave per 256-long dot) + Wu transpose ----------
__global__ __launch_bounds__(256) void precompA(
    const float* __restrict__ ts, const int* __restrict__ user,
    const float* __restrict__ user_pref,
    const float* __restrict__ Wq, const float* __restrict__ bq,
    const float* __restrict__ Wk, const float* __restrict__ bk,
    const float* __restrict__ Wv, const float* __restrict__ bv,
    const float* __restrict__ Wu, float* __restrict__ ws)
{
    int tid = threadIdx.x;
    if (blockIdx.x >= 8704) {                 // Wu transpose: 256 blocks
        int o = (blockIdx.x - 8704) * 256 + tid;   // o = j*256 + d
        ws[WUT_OFF + o] = Wu[(o & 255) * 256 + (o >> 8)];
        return;
    }
    int lane = tid & 63;
    int gw = blockIdx.x * 4 + (tid >> 6);     // global wave id, 0..34815
    const float* wrow; const float* x; float bias = 0.f; float* outp;
    if (gw < 16384) {                         // qu: b = gw>>8, j = gw&255
        int b = gw >> 8, j = gw & 255;
        wrow = Wq + j * 512;                  // first 256 cols (user part)
        x = user_pref + (long long)user[b] * 256;
        outp = ws + QU_OFF + gw;
    } else if (gw < 22528) {                  // qt
        int r = gw - 16384, t = r >> 8, j = r & 255;
        wrow = Wq + j * 512 + 256;            // time part
        x = ts + t * 256; bias = bq[j];
        outp = ws + QT_OFF + r;
    } else if (gw < 28672) {                  // kk  -> layout [h][t][hd]
        int r = gw - 22528, t = r >> 8, j = r & 255;
        wrow = Wk + j * 256; x = ts + t * 256; bias = bk[j];
        outp = ws + KK_OFF + ((j >> 6) * 24 + t) * 64 + (j & 63);
    } else {                                  // vv
        int r = gw - 28672, t = r >> 8, j = r & 255;
        wrow = Wv + j * 256; x = ts + t * 256; bias = bv[j];
        outp = ws + VV_OFF + ((j >> 6) * 24 + t) * 64 + (j & 63);
    }
    float s = 0.f;
    #pragma unroll
    for (int i = 0; i < 4; ++i) s = fmaf(wrow[lane + 64 * i], x[lane + 64 * i], s);
    #pragma unroll
    for (int off = 32; off; off >>= 1) s += __shfl_xor(s, off);
    if (lane == 0) *outp = s + bias;
}

// ---------- Kernel B: folded tables (vW, EU, ET), one thread per output ----------
__global__ __launch_bounds__(256) void precompB(float* __restrict__ ws)
{
    const float* qu  = ws + QU_OFF;
    const float* qt  = ws + QT_OFF;
    const float* kk  = ws + KK_OFF;
    const float* vv  = ws + VV_OFF;
    const float* WuT = ws + WUT_OFF;
    int o = blockIdx.x * 256 + threadIdx.x;
    if (o < 24576) {                          // vW[ht][d]
        int ht = o >> 8, d = o & 255;
        int h = ht / 24;
        const float* vp = vv + ht * 64;
        const float* wp = WuT + (h * 64) * 256 + d;
        float s = 0.f;
        #pragma unroll 8
        for (int hd = 0; hd < 64; ++hd) s = fmaf(vp[hd], wp[hd * 256], s);
        ws[VW_OFF + o] = s;
    } else if (o < 30720) {                   // EU[b][h*24+t]
        int o2 = o - 24576;
        int b = o2 / 96, rem = o2 - b * 96, h = rem / 24;
        const float* qp = qu + b * 256 + h * 64;
        const float* kp = kk + rem * 64;
        float s = 0.f;
        #pragma unroll 8
        for (int hd = 0; hd < 64; ++hd) s = fmaf(qp[hd], kp[hd], s);
        ws[EU_OFF + o2] = expf(s * 0.125f);
    } else if (o < 33024) {                   // ET[t'][h*24+t]
        int o3 = o - 30720;
        int tp = o3 / 96, rem = o3 - tp * 96, h = rem / 24;
        const float* qp = qt + tp * 256 + h * 64;
        const float* kp = kk + rem * 64;
        float s = 0.f;
        #pragma unroll 8
        for (int hd = 0; hd < 64; ++hd) s = fmaf(qp[hd], kp[hd], s);
        ws[ET_OFF + o3] = expf(s * 0.125f);
    }
}

// ---------- Kernel C: per-token softmax (no exp!) + [64x96]x[96x256] fp32 GEMM ----------
__global__ __launch_bounds__(256) void attn_main(
    const int* __restrict__ hour, const int* __restrict__ hour_mask,
    const float* __restrict__ ws, const float* __restrict__ bu,
    float* __restrict__ out)
{
    const float* EU = ws + EU_OFF;
    const float* ET = ws + ET_OFF;
    const float* vW = ws + VW_OFF;
    __shared__ float attn_s[96][64];          // [ht][tok] 24 KB
    int tid = threadIdx.x;
    int nb = blockIdx.x * 64;                 // 64 tokens per block; all same b (64|512)
    int b = nb >> 9;
    // ---- phase 1: attention weights, thread = (tok, h) ----
    {
        int tok = tid >> 2, h = tid & 3;
        int n = nb + tok;
        int th = hour[n];
        const float4* EUp = (const float4*)(EU + b * 96 + h * 24);
        const float4* ETp = (const float4*)(ET + th * 96 + h * 24);
        const int4*   mp  = (const int4*)(hour_mask + n * 24);
        float p[24]; float ssum = 0.f;
        #pragma unroll
        for (int q = 0; q < 6; ++q) {
            float4 e = EUp[q]; float4 f = ETp[q]; int4 m = mp[q];
            float v0 = (m.x != 0) ? 0.f : e.x * f.x;
            float v1 = (m.y != 0) ? 0.f : e.y * f.y;
            float v2 = (m.z != 0) ? 0.f : e.z * f.z;
            float v3 = (m.w != 0) ? 0.f : e.w * f.w;
            p[q*4+0] = v0; p[q*4+1] = v1; p[q*4+2] = v2; p[q*4+3] = v3;
            ssum += (v0 + v1) + (v2 + v3);
        }
        float r = 1.0f / ssum;
        #pragma unroll
        for (int t = 0; t < 24; ++t) attn_s[h * 24 + t][tok] = p[t] * r;
    }
    __syncthreads();
    // ---- phase 2: out[tok][d] = attn . vW + bu ----
    int dg = tid & 31, tg = tid >> 5;
    int lo = dg * 4;                          // d-slice = {lo..lo+3} U {128+lo..128+lo+3}
    float acc[8][8];
    #pragma unroll
    for (int j = 0; j < 8; ++j)
        #pragma unroll
        for (int i = 0; i < 8; ++i) acc[j][i] = 0.f;
    const float* vWp = vW + lo;
    // software-pipelined: prefetch ht+1 while doing FMAs of ht
    float4 wa = *(const float4*)(vWp);
    float4 wb = *(const float4*)(vWp + 128);
    float4 aa = *(const float4*)(&attn_s[0][tg * 8]);
    float4 ab = *(const float4*)(&attn_s[0][tg * 8 + 4]);
    #pragma unroll 2
    for (int ht = 0; ht < 95; ++ht) {
        float4 wa_n = *(const float4*)(vWp + (ht + 1) * 256);
        float4 wb_n = *(const float4*)(vWp + (ht + 1) * 256 + 128);
        float4 aa_n = *(const float4*)(&attn_s[ht + 1][tg * 8]);
        float4 ab_n = *(const float4*)(&attn_s[ht + 1][tg * 8 + 4]);
        float a[8] = {aa.x, aa.y, aa.z, aa.w, ab.x, ab.y, ab.z, ab.w};
        float w[8] = {wa.x, wa.y, wa.z, wa.w, wb.x, wb.y, wb.z, wb.w};
        #pragma unroll
        for (int j = 0; j < 8; ++j)
            #pragma unroll
            for (int i = 0; i < 8; ++i)
                acc[j][i] = fmaf(a[j], w[i], acc[j][i]);
        wa = wa_n; wb = wb_n; aa = aa_n; ab = ab_n;
    }
    {   // last ht = 95
        float a[8] = {aa.x, aa.y, aa.z, aa.w, ab.x, ab.y, ab.z, ab.w};
        float w[8] = {wa.x, wa.y, wa.z, wa.w, wb.x, wb.y, wb.z, wb.w};
        #pragma unroll
        for (int j = 0; j < 8; ++j)
            #pragma unroll
            for (int i = 0; i < 8; ++i)
                acc[j][i] = fmaf(a[j], w[i], acc[j][i]);
    }
    // ---- epilogue: + bu, coalesced float4 stores ----
    float4 bua = *(const float4*)(bu + lo);
    float4 bub = *(const float4*)(bu + 128 + lo);
    #pragma unroll
    for (int j = 0; j < 8; ++j) {
        float* op = out + (size_t)(nb + tg * 8 + j) * 256;
        float4 r0 = make_float4(acc[j][0] + bua.x, acc[j][1] + bua.y,
                                acc[j][2] + bua.z, acc[j][3] + bua.w);
        float4 r1 = make_float4(acc[j][4] + bub.x, acc[j][5] + bub.y,
                                acc[j][6] + bub.z, acc[j][7] + bub.w);
        *(float4*)(op + lo) = r0;
        *(float4*)(op + 128 + lo) = r1;
    }
}

extern "C" void kernel_launch(void* const* d_in, const int* in_sizes, int n_in,
                              void* d_out, int out_size, void* d_ws, size_t ws_size,
                              hipStream_t stream)
{
    const float* ts        = (const float*)d_in[0];
    const int*   user      = (const int*)  d_in[1];
    const int*   hour      = (const int*)  d_in[2];
    const int*   hour_mask = (const int*)  d_in[3];
    const float* user_pref = (const float*)d_in[4];
    const float* Wq        = (const float*)d_in[5];
    const float* bq        = (const float*)d_in[6];
    const float* Wk        = (const float*)d_in[7];
    const float* bk        = (const float*)d_in[8];
    const float* Wv        = (const float*)d_in[9];
    const float* bv        = (const float*)d_in[10];
    const float* Wu        = (const float*)d_in[11];
    const float* bu        = (const float*)d_in[12];
    float* ws  = (float*)d_ws;
    float* out = (float*)d_out;

    hipLaunchKernelGGL(precompA, dim3(8960), dim3(256), 0, stream,
                       ts, user, user_pref, Wq, bq, Wk, bk, Wv, bv, Wu, ws);
    hipLaunchKernelGGL(precompB, dim3(129), dim3(256), 0, stream, ws);
    hipLaunchKernelGGL(attn_main, dim3(512), dim3(256), 0, stream,
                       hour, hour_mask, ws, bu, out);
}

// Round 2
// 26.120 us; speedup vs baseline: 1.7190x; 1.7190x over previous
//
#include <hip/hip_runtime.h>
#include <hip/hip_bf16.h>

// B=64, S=512, N=32768, D=256, H=4, HD=64, T=24, scale=1/8.
//
// Workspace layout (float offsets):
//   qu  [64][256]        @ 0       (16384)  Wq(:, :256) @ user_pref[user[b]]
//   qt  [24][256]        @ 16384   (6144)   Wq(:, 256:) @ ts[t] + bq
//   kk  [96][64]         @ 22528   (6144)   (h*24+t major) Wk @ ts + bk
//   vv  [96][64]         @ 28672   (6144)   Wv @ ts + bv
//   EU  [64][4][24]      @ 34816   (6144)   exp(scale * qu.k)
//   ET  [24][4][24]      @ 40960   (2304)   exp(scale * qt.k)
//   vWB [96x256 bf16]    @ 43264   (12288 floats) folded V*Wu in MFMA-B fragment layout
#define QU_OFF   0
#define QT_OFF   16384
#define KK_OFF   22528
#define VV_OFF   28672
#define EU_OFF   34816
#define ET_OFF   40960
#define VWB_OFF  43264

typedef __attribute__((ext_vector_type(8))) short bf16x8;
typedef __attribute__((ext_vector_type(4))) float f32x4;

__device__ __forceinline__ unsigned short f2bf(float f) {
    unsigned u = __builtin_bit_cast(unsigned, f);
    return (unsigned short)((u + 0x7FFFu + ((u >> 16) & 1u)) >> 16);
}

// ---------- Kernel A: projection rows (one wave per 256-long dot) ----------
__global__ __launch_bounds__(256) void precompA(
    const float* __restrict__ ts, const int* __restrict__ user,
    const float* __restrict__ user_pref,
    const float* __restrict__ Wq, const float* __restrict__ bq,
    const float* __restrict__ Wk, const float* __restrict__ bk,
    const float* __restrict__ Wv, const float* __restrict__ bv,
    float* __restrict__ ws)
{
    int tid = threadIdx.x;
    int lane = tid & 63;
    int gw = blockIdx.x * 4 + (tid >> 6);     // global wave id, 0..34815
    const float* wrow; const float* x; float bias = 0.f; float* outp;
    if (gw < 16384) {                         // qu: b = gw>>8, j = gw&255
        int b = gw >> 8, j = gw & 255;
        wrow = Wq + j * 512;                  // user part (first 256 cols)
        x = user_pref + (long long)user[b] * 256;
        outp = ws + QU_OFF + gw;
    } else if (gw < 22528) {                  // qt
        int r = gw - 16384, t = r >> 8, j = r & 255;
        wrow = Wq + j * 512 + 256; x = ts + t * 256; bias = bq[j];
        outp = ws + QT_OFF + r;
    } else if (gw < 28672) {                  // kk -> [h*24+t][hd]
        int r = gw - 22528, t = r >> 8, j = r & 255;
        wrow = Wk + j * 256; x = ts + t * 256; bias = bk[j];
        outp = ws + KK_OFF + ((j >> 6) * 24 + t) * 64 + (j & 63);
    } else {                                  // vv -> [h*24+t][hd]
        int r = gw - 28672, t = r >> 8, j = r & 255;
        wrow = Wv + j * 256; x = ts + t * 256; bias = bv[j];
        outp = ws + VV_OFF + ((j >> 6) * 24 + t) * 64 + (j & 63);
    }
    float s = 0.f;
    #pragma unroll
    for (int i = 0; i < 4; ++i) s = fmaf(wrow[lane + 64 * i], x[lane + 64 * i], s);
    #pragma unroll
    for (int off = 32; off; off >>= 1) s += __shfl_xor(s, off);
    if (lane == 0) *outp = s + bias;
}

// ---------- Kernel B: folded tables (vWB bf16 B-frag layout, EU, ET) ----------
__global__ __launch_bounds__(256) void precompB(float* __restrict__ ws,
                                                const float* __restrict__ Wu)
{
    const float* qu = ws + QU_OFF;
    const float* qt = ws + QT_OFF;
    const float* kk = ws + KK_OFF;
    const float* vv = ws + VV_OFF;
    int o = blockIdx.x * 256 + threadIdx.x;
    if (o < 12288) {                          // vWB: thread = (ht-pair, d)
        int htp = o >> 8, d = o & 255;
        int ht = htp * 2;
        int h = ht / 24;                      // pair never crosses h (24 even)
        const float4* v0 = (const float4*)(vv + ht * 64);
        const float4* v1 = (const float4*)(vv + ht * 64 + 64);
        const float4* wp = (const float4*)(Wu + d * 256 + h * 64);
        float s0 = 0.f, s1 = 0.f;
        #pragma unroll
        for (int i = 0; i < 16; ++i) {
            float4 wv = wp[i], a = v0[i], c = v1[i];
            s0 = fmaf(a.x, wv.x, fmaf(a.y, wv.y, fmaf(a.z, wv.z, fmaf(a.w, wv.w, s0))));
            s1 = fmaf(c.x, wv.x, fmaf(c.y, wv.y, fmaf(c.z, wv.z, fmaf(c.w, wv.w, s1))));
        }
        // B-frag layout: element (k=ht, col=d) -> lane=(d&15)+16*((ht>>3)&3), j=ht&7
        int kt = ht >> 5, nt = d >> 4, lg = (ht >> 3) & 3, jh = (ht & 7) >> 1;
        unsigned pack = (unsigned)f2bf(s0) | ((unsigned)f2bf(s1) << 16);
        ((unsigned*)(ws + VWB_OFF))[(kt * 16 + nt) * 256 + ((d & 15) + 16 * lg) * 4 + jh] = pack;
    } else if (o < 18432) {                   // EU[b][h*24+t]
        int o2 = o - 12288;
        int b = o2 / 96, rem = o2 - b * 96;
        const float* qp = qu + b * 256 + (rem / 24) * 64;
        const float* kp = kk + rem * 64;
        float s = 0.f;
        #pragma unroll 8
        for (int hd = 0; hd < 64; ++hd) s = fmaf(qp[hd], kp[hd], s);
        ws[EU_OFF + o2] = expf(s * 0.125f);
    } else if (o < 20736) {                   // ET[t'][h*24+t]
        int o3 = o - 18432;
        int tp = o3 / 96, rem = o3 - tp * 96;
        const float* qp = qt + tp * 256 + (rem / 24) * 64;
        const float* kp = kk + rem * 64;
        float s = 0.f;
        #pragma unroll 8
        for (int hd = 0; hd < 64; ++hd) s = fmaf(qp[hd], kp[hd], s);
        ws[ET_OFF + o3] = expf(s * 0.125f);
    }
}

// ---------- Kernel C: softmax (no exp) -> A-frag LDS -> MFMA GEMM [64x96]x[96x256] ----------
__global__ __launch_bounds__(256) void attn_mfma(
    const int* __restrict__ hour, const int* __restrict__ hour_mask,
    const float* __restrict__ ws, const float* __restrict__ bu,
    float* __restrict__ out)
{
    const float* EU = ws + EU_OFF;
    const float* ET = ws + ET_OFF;
    __shared__ int4 A_lds[12 * 64];           // 12 KB: [kt*4+mt][lane] 16B frags
    int tid = threadIdx.x;
    int nb = blockIdx.x * 64;                 // 64 tokens/block, all same b
    int b = nb >> 9;
    // ---- phase 1: attention probs, thread = (tok, h); write bf16 A-fragments ----
    {
        int tok = tid >> 2, h = tid & 3;
        int n = nb + tok;
        int th = hour[n];
        const float4* EUp = (const float4*)(EU + b * 96 + h * 24);
        const float4* ETp = (const float4*)(ET + th * 96 + h * 24);
        const int4*   mp  = (const int4*)(hour_mask + (long long)n * 24);
        float p[24]; float ssum = 0.f;
        #pragma unroll
        for (int q = 0; q < 6; ++q) {
            float4 e = EUp[q]; float4 f = ETp[q]; int4 m = mp[q];
            float v0 = (m.x != 0) ? 0.f : e.x * f.x;
            float v1 = (m.y != 0) ? 0.f : e.y * f.y;
            float v2 = (m.z != 0) ? 0.f : e.z * f.z;
            float v3 = (m.w != 0) ? 0.f : e.w * f.w;
            p[q*4+0] = v0; p[q*4+1] = v1; p[q*4+2] = v2; p[q*4+3] = v3;
            ssum += (v0 + v1) + (v2 + v3);
        }
        float r = 1.0f / ssum;
        int mt = tok >> 4, tl = tok & 15;
        #pragma unroll
        for (int tp = 0; tp < 12; ++tp) {
            int ht = h * 24 + tp * 2;         // even; pair (ht, ht+1)
            unsigned pack = (unsigned)f2bf(p[tp*2] * r)
                          | ((unsigned)f2bf(p[tp*2+1] * r) << 16);
            int kt = ht >> 5, lg = (ht >> 3) & 3, jh = (ht & 7) >> 1;
            ((unsigned*)A_lds)[((kt * 4 + mt) * 64 + tl + 16 * lg) * 4 + jh] = pack;
        }
    }
    __syncthreads();
    // ---- phase 2: per wave: 4 M-tiles x 4 N-tiles x 3 K-chunks of 16x16x32 MFMA ----
    int w = tid >> 6, l = tid & 63;
    const int4* Bg = (const int4*)(ws + VWB_OFF);
    bf16x8 afr[3][4], bfr[3][4];
    #pragma unroll
    for (int kt = 0; kt < 3; ++kt)
        #pragma unroll
        for (int q = 0; q < 4; ++q) {
            afr[kt][q] = __builtin_bit_cast(bf16x8, A_lds[(kt * 4 + q) * 64 + l]);
            bfr[kt][q] = __builtin_bit_cast(bf16x8, Bg[(kt * 16 + w * 4 + q) * 64 + l]);
        }
    f32x4 acc[4][4];
    #pragma unroll
    for (int mt = 0; mt < 4; ++mt)
        #pragma unroll
        for (int q = 0; q < 4; ++q) acc[mt][q] = (f32x4)0.f;
    #pragma unroll
    for (int kt = 0; kt < 3; ++kt)
        #pragma unroll
        for (int mt = 0; mt < 4; ++mt)
            #pragma unroll
            for (int q = 0; q < 4; ++q)
                acc[mt][q] = __builtin_amdgcn_mfma_f32_16x16x32_bf16(
                    afr[kt][mt], bfr[kt][q], acc[mt][q], 0, 0, 0);
    // ---- epilogue: + bu, store (D: col=l&15, row=(l>>4)*4+reg) ----
    int colb = w * 64 + (l & 15);
    float buv[4];
    #pragma unroll
    for (int q = 0; q < 4; ++q) buv[q] = bu[colb + q * 16];
    int row0 = nb + (l >> 4) * 4;
    #pragma unroll
    for (int mt = 0; mt < 4; ++mt)
        #pragma unroll
        for (int q = 0; q < 4; ++q) {
            float* op = out + (size_t)(row0 + mt * 16) * 256 + colb + q * 16;
            #pragma unroll
            for (int r = 0; r < 4; ++r)
                op[(size_t)r * 256] = acc[mt][q][r] + buv[q];
        }
}

extern "C" void kernel_launch(void* const* d_in, const int* in_sizes, int n_in,
                              void* d_out, int out_size, void* d_ws, size_t ws_size,
                              hipStream_t stream)
{
    const float* ts        = (const float*)d_in[0];
    const int*   user      = (const int*)  d_in[1];
    const int*   hour      = (const int*)  d_in[2];
    const int*   hour_mask = (const int*)  d_in[3];
    const float* user_pref = (const float*)d_in[4];
    const float* Wq        = (const float*)d_in[5];
    const float* bq        = (const float*)d_in[6];
    const float* Wk        = (const float*)d_in[7];
    const float* bk        = (const float*)d_in[8];
    const float* Wv        = (const float*)d_in[9];
    const float* bv        = (const float*)d_in[10];
    const float* Wu        = (const float*)d_in[11];
    const float* bu        = (const float*)d_in[12];
    float* ws  = (float*)d_ws;
    float* out = (float*)d_out;

    hipLaunchKernelGGL(precompA, dim3(8704), dim3(256), 0, stream,
                       ts, user, user_pref, Wq, bq, Wk, bk, Wv, bv, ws);
    hipLaunchKernelGGL(precompB, dim3(81), dim3(256), 0, stream, ws, Wu);
    hipLaunchKernelGGL(attn_mfma, dim3(512), dim3(256), 0, stream,
                       hour, hour_mask, ws, bu, out);
}